// Round 6
// baseline (157.603 us; speedup 1.0000x reference)
//
#include <hip/hip_runtime.h>

#define HH 128
#define WW 128
#define BB 64
#define OO 32

typedef float v2f __attribute__((ext_vector_type(2)));

// Block = (b, group of 4 o's): 512 blocks x 1024 threads -> 2 resident
// blocks/CU (2 x 64 KiB LDS), 32 waves/CU. Each thread computes 4 consecutive
// w pixels (one float4 store) for rows h0 + {0,32,64,96}. Coordinates advance
// incrementally (packed f32 adds); clamp into [0,126.99999] replaces the
// reference's index clamp (equivalent within ~1e-5 tap weight) so each
// bilinear row-pair is one ds_read2_b32 and +1/+128 taps stay in-bounds.
__launch_bounds__(1024, 8)
__global__ void sample_kernel(const float* __restrict__ X,
                              const float* __restrict__ eps,
                              const float* __restrict__ tmin,
                              const float* __restrict__ tmax,
                              float* __restrict__ out) {
    __shared__ float img[HH * WW];   // 64 KiB
    __shared__ float scoef[4][6];

    const int bid = blockIdx.x;
    const int og  = bid & 7;          // consecutive blocks share b -> L2 reuse
    const int b   = bid >> 3;
    const int tid = threadIdx.x;

    if (tid < 4) {
        const int o = og * 4 + tid;
        float th[7];
#pragma unroll
        for (int i = 0; i < 7; ++i) {
            const float mn = tmin[i], mx = tmax[i];
            th[i] = mn + (mx - mn) * eps[o * 7 + i];
        }
        const float ang = th[0], sx = th[1], sy = th[2], px = th[3],
                    py = th[4], tx = th[5], ty = th[6];
        const float c = cosf(ang), s = sinf(ang);
        const float half = 0.5f * (WW - 1);  // 63.5
        scoef[tid][0] = (c * sx - s * py) * half;   // cx0
        scoef[tid][1] = (c * px - s * sy) * half;   // cx1
        scoef[tid][2] = (tx + 1.0f) * half;         // cxt
        scoef[tid][3] = (s * sx + c * py) * half;   // cy0
        scoef[tid][4] = (s * px + c * sy) * half;   // cy1
        scoef[tid][5] = (ty + 1.0f) * half;         // cyt
    }

    // Stage image b -> LDS, coalesced float4 (4 per thread)
    {
        const float4* __restrict__ src = (const float4*)(X + b * (HH * WW));
        float4* dst = (float4*)img;
#pragma unroll
        for (int i = 0; i < 4; ++i)
            dst[tid + i * 1024] = src[tid + i * 1024];
    }
    __syncthreads();

    const int w4 = (tid & 31) << 2;          // 0,4,...,124
    const int h0 = tid >> 5;                 // 0..31
    const float step = 2.0f / 127.0f;
    const float Xg0 = -1.0f + w4 * step;
    const float Yg0 = -1.0f + h0 * step;
    const float hi  = 126.999992f;           // nextbelow(127)

#pragma unroll
    for (int j = 0; j < 4; ++j) {
        const int o = og * 4 + j;
        const float cx0 = scoef[j][0];
        const float cx1 = scoef[j][1];
        const float cxt = scoef[j][2];
        const float cy0 = scoef[j][3];
        const float cy1 = scoef[j][4];
        const float cyt = scoef[j][5];

        v2f xy_row;                           // coords at (h0, w4)
        xy_row.x = fmaf(cx1, Yg0, fmaf(cx0, Xg0, cxt));
        xy_row.y = fmaf(cy1, Yg0, fmaf(cy0, Xg0, cyt));
        v2f dxy_w = {cx0 * step, cy0 * step};                      // per-pixel along w
        v2f dxy_h = {cx1 * (32.0f * step), cy1 * (32.0f * step)};  // per 32-row i-step

        float4* __restrict__ outp = (float4*)(
            out + ((size_t)(o * BB + b) * (HH * WW)) + h0 * WW + w4);

#pragma unroll
        for (int i = 0; i < 4; ++i) {
            v2f xy = xy_row;
            float4 r;
            float* rp = &r.x;
#pragma unroll
            for (int p = 0; p < 4; ++p) {
                v2f xyc;
                xyc.x = __builtin_amdgcn_fmed3f(xy.x, 0.0f, hi);
                xyc.y = __builtin_amdgcn_fmed3f(xy.y, 0.0f, hi);
                const v2f fl  = __builtin_elementwise_floor(xyc);
                const v2f wxy = xyc - fl;                 // v_pk_add (neg)
                const int idx = (int)fmaf(fl.y, 128.0f, fl.x);  // exact (<2^24)

                const float Ia = img[idx];
                const float Ic = img[idx + 1];        // ds_read2_b32 with Ia
                const float Ib = img[idx + WW];
                const float Id = img[idx + WW + 1];   // ds_read2_b32 with Ib

                const v2f AB = {Ia, Ib};
                const v2f CD = {Ic, Id};
                const v2f d  = CD - AB;                   // v_pk_add (neg)
                const v2f wxx = {wxy.x, wxy.x};
                const v2f r2 = __builtin_elementwise_fma(wxx, d, AB);  // v_pk_fma
                rp[p] = fmaf(wxy.y, r2.y - r2.x, r2.x);

                xy += dxy_w;                              // v_pk_add
            }
            *outp = r;
            outp += 32 * WW / 4;   // advance 32 rows (float4 units!)
            xy_row += dxy_h;       // v_pk_add
        }
    }
}

extern "C" void kernel_launch(void* const* d_in, const int* in_sizes, int n_in,
                              void* d_out, int out_size, void* d_ws, size_t ws_size,
                              hipStream_t stream) {
    const float* X    = (const float*)d_in[0];
    const float* eps  = (const float*)d_in[1];
    const float* tmin = (const float*)d_in[2];
    const float* tmax = (const float*)d_in[3];
    float* out = (float*)d_out;

    const int nblocks = BB * 8;  // 512: 2 per CU (LDS-capped), 32 waves/CU
    sample_kernel<<<nblocks, 1024, 0, stream>>>(X, eps, tmin, tmax, out);
}